// Round 7
// baseline (106.262 us; speedup 1.0000x reference)
//
#include <hip/hip_runtime.h>

// ConvCapsLayer: A=32,B=32,K=3,P=4,STRIDE=2,ITERS=3 — all fp32
// x: (2,32,32,512) f32   weights: (288,32,16) f32   out: (450,512) f32
// One WAVE per (patch n, j-PAIR (j0,j0+1)): two independent routing chains
// interleaved for 2x intra-wave ILP (latency-bound per R6 counters).
// Lane owns i = lane + 64k, k=0..4 (k=4 only lane<32). v[2][5][8] packed v2f.
// Unnormalized softmax (SE rides butterfly), split-first butterfly -> comp=lane&15.
// No LDS, no __syncthreads, packed fp32 math.
// NOTE: __launch_bounds__ min-waves must keep VGPR cap >= live set (~220);
// (256,2) -> 256 cap. Forcing tighter spilled 170MB to scratch (measured R4).

#define OH 15
#define OW 15
#define NITERS 3
#define EPS_ 1e-8f

typedef float v2f __attribute__((ext_vector_type(2)));

__device__ __forceinline__ v2f pfma(float a, v2f b, v2f c) {
    return __builtin_elementwise_fma((v2f){a, a}, b, c);
}

__global__ __launch_bounds__(256, 2) void convcaps_kernel(
    const float* __restrict__ x,   // (2,32,32,512)
    const float* __restrict__ w,   // (288,32,16)
    float* __restrict__ out)       // (450,512)
{
    const int blk  = blockIdx.x;      // 0..1799
    const int n    = blk >> 2;        // patch 0..449
    const int jg   = blk & 3;
    const int t    = threadIdx.x;
    const int wv   = t >> 6;          // 0..3
    const int lane = t & 63;
    const int j0   = jg * 8 + wv * 2; // this wave: capsules j0, j0+1

    const int batch = n / (OH * OW);
    const int rem   = n - batch * OH * OW;
    const int oy    = rem / OW;
    const int ox    = rem - oy * OW;

    const bool has5 = (lane < 32);

    v2f v[2][5][8];                   // [chain][k][p*2+qq]
    float logit[2][5] = {{0.f,0.f,0.f,0.f,0.f},{0.f,0.f,0.f,0.f,0.f}};

    // ---- transform: v[c][k] = X_i(4x4) * W_{i,j0+c}(4x4), i = lane+64k ----
#pragma unroll
    for (int k = 0; k < 5; ++k) {
        if (k == 4 && !has5) {
#pragma unroll
            for (int m = 0; m < 8; ++m) {
                v[0][4][m] = (v2f){0.f, 0.f};
                v[1][4][m] = (v2f){0.f, 0.f};
            }
        } else {
            const int i  = lane + 64 * k;
            const int a  = i & 31;
            const int kw = (i >> 5) % 3;
            const int kh = i / 96;
            const int h  = oy * 2 + kh;
            const int wc = ox * 2 + kw;

            const float4* xv = reinterpret_cast<const float4*>(
                x + (((size_t)(batch * 32 + h) * 32 + wc) * 512 + a * 16));
            float4 x0 = xv[0], x1 = xv[1], x2 = xv[2], x3 = xv[3];
            float xr[16] = { x0.x,x0.y,x0.z,x0.w, x1.x,x1.y,x1.z,x1.w,
                             x2.x,x2.y,x2.z,x2.w, x3.x,x3.y,x3.z,x3.w };

            // w rows for j0 and j0+1: 32 contiguous floats (128B per lane)
            const float4* wp = reinterpret_cast<const float4*>(
                w + ((size_t)i * 32 + j0) * 16);
            float4 a0 = wp[0], a1 = wp[1], a2 = wp[2], a3 = wp[3];
            float4 b0 = wp[4], b1 = wp[5], b2 = wp[6], b3 = wp[7];
            v2f wr[2][4][2] = {
                { {{a0.x,a0.y},{a0.z,a0.w}}, {{a1.x,a1.y},{a1.z,a1.w}},
                  {{a2.x,a2.y},{a2.z,a2.w}}, {{a3.x,a3.y},{a3.z,a3.w}} },
                { {{b0.x,b0.y},{b0.z,b0.w}}, {{b1.x,b1.y},{b1.z,b1.w}},
                  {{b2.x,b2.y},{b2.z,b2.w}}, {{b3.x,b3.y},{b3.z,b3.w}} } };

#pragma unroll
            for (int c = 0; c < 2; ++c)
#pragma unroll
                for (int p = 0; p < 4; ++p)
#pragma unroll
                    for (int qq = 0; qq < 2; ++qq) {
                        v2f acc = (v2f){0.f, 0.f};
                        acc = pfma(xr[p*4+0], wr[c][0][qq], acc);
                        acc = pfma(xr[p*4+1], wr[c][1][qq], acc);
                        acc = pfma(xr[p*4+2], wr[c][2][qq], acc);
                        acc = pfma(xr[p*4+3], wr[c][3][qq], acc);
                        v[c][k][p*2+qq] = acc;
                    }
        }
    }

#pragma unroll
    for (int it = 0; it < NITERS; ++it) {
        // ---- unnormalized weighted sums (both chains) ----
        float cb[2][16];
        float se[2];
#pragma unroll
        for (int c = 0; c < 2; ++c) {
            v2f c2[8];
            if (it == 0) {
#pragma unroll
                for (int m = 0; m < 8; ++m)
                    c2[m] = v[c][0][m] + v[c][1][m] + v[c][2][m]
                          + v[c][3][m] + v[c][4][m];
                se[c] = 0.f;  // normalizer is 288 (softmax of zeros)
            } else {
                const float e0 = __expf(logit[c][0]), e1 = __expf(logit[c][1]);
                const float e2 = __expf(logit[c][2]), e3 = __expf(logit[c][3]);
                const float e4 = __expf(logit[c][4]);
#pragma unroll
                for (int m = 0; m < 8; ++m)
                    c2[m] = pfma(e0, v[c][0][m],
                            pfma(e1, v[c][1][m],
                            pfma(e2, v[c][2][m],
                            pfma(e3, v[c][3][m],
                            pfma(e4, v[c][4][m], (v2f){0.f, 0.f})))));
                se[c] = e0 + e1 + e2 + e3 + (has5 ? e4 : 0.f);
            }
#pragma unroll
            for (int m = 0; m < 8; ++m) { cb[c][2*m] = c2[m].x; cb[c][2*m+1] = c2[m].y; }
        }

        // ---- split-first butterflies, both chains interleaved ----
        float seR[2] = { se[0], se[1] };
        float s8[2][8];
        {
            const bool b = lane & 1;
#pragma unroll
            for (int c = 0; c < 2; ++c) {
#pragma unroll
                for (int m = 0; m < 8; ++m) {
                    float send = b ? cb[c][2*m]   : cb[c][2*m+1];
                    float keep = b ? cb[c][2*m+1] : cb[c][2*m];
                    s8[c][m] = keep + __shfl_xor(send, 1);
                }
                seR[c] += __shfl_xor(seR[c], 1);
            }
        }
        float s4[2][4];
        {
            const bool b = (lane >> 1) & 1;
#pragma unroll
            for (int c = 0; c < 2; ++c) {
#pragma unroll
                for (int m = 0; m < 4; ++m) {
                    float send = b ? s8[c][2*m]   : s8[c][2*m+1];
                    float keep = b ? s8[c][2*m+1] : s8[c][2*m];
                    s4[c][m] = keep + __shfl_xor(send, 2);
                }
                seR[c] += __shfl_xor(seR[c], 2);
            }
        }
        float s2v[2][2];
        {
            const bool b = (lane >> 2) & 1;
#pragma unroll
            for (int c = 0; c < 2; ++c) {
#pragma unroll
                for (int m = 0; m < 2; ++m) {
                    float send = b ? s4[c][2*m]   : s4[c][2*m+1];
                    float keep = b ? s4[c][2*m+1] : s4[c][2*m];
                    s2v[c][m] = keep + __shfl_xor(send, 4);
                }
                seR[c] += __shfl_xor(seR[c], 4);
            }
        }
        float s1[2];
        {
            const bool b = (lane >> 3) & 1;
#pragma unroll
            for (int c = 0; c < 2; ++c) {
                float send = b ? s2v[c][0] : s2v[c][1];
                float keep = b ? s2v[c][1] : s2v[c][0];
                s1[c] = keep + __shfl_xor(send, 8);
                seR[c] += __shfl_xor(seR[c], 8);
            }
        }
#pragma unroll
        for (int c = 0; c < 2; ++c) {
            s1[c] += __shfl_xor(s1[c], 16);  seR[c] += __shfl_xor(seR[c], 16);
            s1[c] += __shfl_xor(s1[c], 32);  seR[c] += __shfl_xor(seR[c], 32);
        }
        // s1[c] = sum_i (e_i or 1) * v_i[comp], comp = lane&15 ; seR[c] = SE

        // ---- squash (both chains) ----
        float pv[2];
#pragma unroll
        for (int c = 0; c < 2; ++c) {
            const float s = (it == 0) ? s1[c] * (1.0f / 288.0f) : s1[c] / seR[c];
            float t2 = s * s;
            t2 += __shfl_xor(t2, 1);
            t2 += __shfl_xor(t2, 2);
            t2 += __shfl_xor(t2, 4);
            t2 += __shfl_xor(t2, 8);
            const float scale = t2 / ((1.0f + t2) * sqrtf(t2 + EPS_));
            pv[c] = s * scale;            // comp (lane&15) of p, chain c
        }

        if (it < NITERS - 1) {
            // broadcast p[16] per chain (readlane: comp q lives at lane q)
            float p[2][16];
#pragma unroll
            for (int q = 0; q < 16; ++q) {
                p[0][q] = __shfl(pv[0], q);
                p[1][q] = __shfl(pv[1], q);
            }
#pragma unroll
            for (int c = 0; c < 2; ++c) {
                v2f p2[8];
#pragma unroll
                for (int m = 0; m < 8; ++m) p2[m] = (v2f){p[c][2*m], p[c][2*m+1]};
#pragma unroll
                for (int k = 0; k < 5; ++k) {
                    v2f acc = (v2f){0.f, 0.f};
#pragma unroll
                    for (int m = 0; m < 8; ++m)
                        acc = __builtin_elementwise_fma(v[c][k][m], p2[m], acc);
                    logit[c][k] += acc.x + acc.y;
                }
            }
        } else {
            // lanes 0..15 -> chain 0 comps, lanes 16..31 -> chain 1 comps
            if (lane < 32)
                out[(size_t)n * 512 + j0 * 16 + lane] = (lane < 16) ? pv[0] : pv[1];
        }
    }
}

extern "C" void kernel_launch(void* const* d_in, const int* in_sizes, int n_in,
                              void* d_out, int out_size, void* d_ws, size_t ws_size,
                              hipStream_t stream) {
    const float* x = (const float*)d_in[0];
    const float* w = (const float*)d_in[1];
    float* out = (float*)d_out;
    const int nblocks = 450 * 4;   // (n) x (4 j-groups; wave = j-pair)
    convcaps_kernel<<<nblocks, 256, 0, stream>>>(x, w, out);
}

// Round 8
// 93.619 us; speedup vs baseline: 1.1350x; 1.1350x over previous
//
#include <hip/hip_runtime.h>

// ConvCapsLayer: A=32,B=32,K=3,P=4,STRIDE=2,ITERS=3 — all fp32
// x: (2,32,32,512) f32   weights: (288,32,16) f32   out: (450,512) f32
//
// R8: R7 showed the kernel is TA-pipe bound: per-lane 16B loads at 64B/512B
// lane stride touch ~64 cache lines per instruction (~2560 line-touches/wave
// ~= the whole 57µs). Fix: permute x and w into d_ws so every dwordx4 load is
// lane-contiguous (16 lines/instr):
//   x_t[pixel][m][a][4]  (8 MB)      w_t[j][k][m][lane][4]  (640 KB)
// Main kernel = R6 structure (one wave per (n,j), v[5][8] v2f, split-first
// butterfly, no LDS/barriers, 84 VGPR).
// NOTE: __launch_bounds__ min-waves must keep VGPR cap >= live set (~84);
// forcing 4 waves/EU (64-VGPR cap) spilled 170MB to scratch (measured R4).

#define OH 15
#define OW 15
#define NITERS 3
#define EPS_ 1e-8f

#define XT_FLOATS (2 * 32 * 32 * 512)          // 2,097,152 floats (8 MB)
#define WT_FLOATS (32 * 5 * 4 * 64 * 4)        // 163,840 floats (640 KB)

typedef float v2f __attribute__((ext_vector_type(2)));

__device__ __forceinline__ v2f pfma(float a, v2f b, v2f c) {
    return __builtin_elementwise_fma((v2f){a, a}, b, c);
}

// ---- permute x: x_t[pixel][m][a][c] = x[pixel][a][m*4+c] ----
__global__ __launch_bounds__(256) void permute_x_kernel(
    const float* __restrict__ x, float* __restrict__ xt)
{
    const int tid = blockIdx.x * 256 + threadIdx.x;   // over XT_FLOATS
    const int pixel = tid >> 9;
    const int r = tid & 511;
    const int m = r >> 7;
    const int a = (r >> 2) & 31;
    const int c = r & 3;
    xt[tid] = x[pixel * 512 + a * 16 + m * 4 + c];
}

// ---- permute w: w_t[j][k][m][L][c] = w[(L+64k)*512f.. ] row m ----
__global__ __launch_bounds__(256) void permute_w_kernel(
    const float* __restrict__ w, float* __restrict__ wt)
{
    const int tid = blockIdx.x * 256 + threadIdx.x;   // over WT_FLOATS
    const int j = tid / 5120;
    const int r = tid - j * 5120;
    const int k = r >> 10;
    const int r2 = r & 1023;
    const int m = r2 >> 8;
    const int L = (r2 >> 2) & 63;
    const int c = r2 & 3;
    const int i = L + 64 * k;
    wt[tid] = (i < 288) ? w[(size_t)i * 512 + j * 16 + m * 4 + c] : 0.f;
}

template <bool PERM>
__global__ __launch_bounds__(256, 3) void convcaps_kernel(
    const float* __restrict__ x,   // PERM ? x_t : x
    const float* __restrict__ w,   // PERM ? w_t : w
    float* __restrict__ out)       // (450,512)
{
    const int blk  = blockIdx.x;      // 0..3599
    const int n    = blk >> 3;        // patch 0..449
    const int jg   = blk & 7;
    const int t    = threadIdx.x;
    const int wv   = t >> 6;          // 0..3
    const int lane = t & 63;
    const int j    = jg * 4 + wv;     // out capsule 0..31

    const int batch = n / (OH * OW);
    const int rem   = n - batch * OH * OW;
    const int oy    = rem / OW;
    const int ox    = rem - oy * OW;

    const bool has5 = (lane < 32);

    v2f v[5][8];                      // v[k][p*2+qq]
    float logit[5] = {0.f, 0.f, 0.f, 0.f, 0.f};

    // ---- v[k] = X_i(4x4) * W_ij(4x4), i = lane + 64k ----
#pragma unroll
    for (int k = 0; k < 5; ++k) {
        if (k == 4 && !has5) {
#pragma unroll
            for (int m = 0; m < 8; ++m) v[4][m] = (v2f){0.f, 0.f};
        } else {
            const int i  = lane + 64 * k;
            const int a  = i & 31;
            const int kw = (i >> 5) % 3;
            const int kh = i / 96;
            const int h  = oy * 2 + kh;
            const int wc = ox * 2 + kw;
            const int pixel = (batch * 32 + h) * 32 + wc;

            float4 x0, x1, x2, x3, w0, w1, w2, w3;
            if (PERM) {
                // x_t[pixel][m][a][4]: float4 idx = m*32 + a (lane-contiguous)
                const float4* xb = reinterpret_cast<const float4*>(
                    x + (size_t)pixel * 512);
                x0 = xb[0*32 + a]; x1 = xb[1*32 + a];
                x2 = xb[2*32 + a]; x3 = xb[3*32 + a];
                // w_t[j][k][m][lane][4]: float4 idx = m*64 + lane
                const float4* wb = reinterpret_cast<const float4*>(
                    w + (size_t)j * 5120 + k * 1024);
                w0 = wb[0*64 + lane]; w1 = wb[1*64 + lane];
                w2 = wb[2*64 + lane]; w3 = wb[3*64 + lane];
            } else {
                const float4* xv = reinterpret_cast<const float4*>(
                    x + ((size_t)pixel * 512 + a * 16));
                x0 = xv[0]; x1 = xv[1]; x2 = xv[2]; x3 = xv[3];
                const float4* wp = reinterpret_cast<const float4*>(
                    w + ((size_t)i * 32 + j) * 16);
                w0 = wp[0]; w1 = wp[1]; w2 = wp[2]; w3 = wp[3];
            }

            float xr[16] = { x0.x,x0.y,x0.z,x0.w, x1.x,x1.y,x1.z,x1.w,
                             x2.x,x2.y,x2.z,x2.w, x3.x,x3.y,x3.z,x3.w };
            v2f wr2[4][2] = { {{w0.x,w0.y},{w0.z,w0.w}},
                              {{w1.x,w1.y},{w1.z,w1.w}},
                              {{w2.x,w2.y},{w2.z,w2.w}},
                              {{w3.x,w3.y},{w3.z,w3.w}} };

#pragma unroll
            for (int p = 0; p < 4; ++p) {
#pragma unroll
                for (int qq = 0; qq < 2; ++qq) {
                    v2f acc = (v2f){0.f, 0.f};
                    acc = pfma(xr[p*4+0], wr2[0][qq], acc);
                    acc = pfma(xr[p*4+1], wr2[1][qq], acc);
                    acc = pfma(xr[p*4+2], wr2[2][qq], acc);
                    acc = pfma(xr[p*4+3], wr2[3][qq], acc);
                    v[k][p*2+qq] = acc;
                }
            }
        }
    }

#pragma unroll
    for (int it = 0; it < NITERS; ++it) {
        // ---- unnormalized weighted sum c2 and (it>0) SE = sum_i e_i ----
        v2f c2[8];
        float se_loc;
        if (it == 0) {
#pragma unroll
            for (int m = 0; m < 8; ++m)
                c2[m] = v[0][m] + v[1][m] + v[2][m] + v[3][m] + v[4][m];
            se_loc = 0.f;  // normalizer is 288 (softmax of zeros)
        } else {
            const float e0 = __expf(logit[0]), e1 = __expf(logit[1]);
            const float e2 = __expf(logit[2]), e3 = __expf(logit[3]);
            const float e4 = __expf(logit[4]);
#pragma unroll
            for (int m = 0; m < 8; ++m)
                c2[m] = pfma(e0, v[0][m],
                        pfma(e1, v[1][m],
                        pfma(e2, v[2][m],
                        pfma(e3, v[3][m],
                        pfma(e4, v[4][m], (v2f){0.f, 0.f})))));
            se_loc = e0 + e1 + e2 + e3 + (has5 ? e4 : 0.f);
        }

        float c[16];
#pragma unroll
        for (int m = 0; m < 8; ++m) { c[2*m] = c2[m].x; c[2*m+1] = c2[m].y; }

        // ---- split-first butterfly: comp bit b -> lane bit b ----
        float seR = se_loc;
        float s8[8];
        {
            const bool b = lane & 1;
#pragma unroll
            for (int m = 0; m < 8; ++m) {
                float send = b ? c[2*m]   : c[2*m+1];
                float keep = b ? c[2*m+1] : c[2*m];
                s8[m] = keep + __shfl_xor(send, 1);
            }
            seR += __shfl_xor(seR, 1);
        }
        float s4[4];
        {
            const bool b = (lane >> 1) & 1;
#pragma unroll
            for (int m = 0; m < 4; ++m) {
                float send = b ? s8[2*m]   : s8[2*m+1];
                float keep = b ? s8[2*m+1] : s8[2*m];
                s4[m] = keep + __shfl_xor(send, 2);
            }
            seR += __shfl_xor(seR, 2);
        }
        float s2v[2];
        {
            const bool b = (lane >> 2) & 1;
#pragma unroll
            for (int m = 0; m < 2; ++m) {
                float send = b ? s4[2*m]   : s4[2*m+1];
                float keep = b ? s4[2*m+1] : s4[2*m];
                s2v[m] = keep + __shfl_xor(send, 4);
            }
            seR += __shfl_xor(seR, 4);
        }
        float s1;
        {
            const bool b = (lane >> 3) & 1;
            float send = b ? s2v[0] : s2v[1];
            float keep = b ? s2v[1] : s2v[0];
            s1 = keep + __shfl_xor(send, 8);
            seR += __shfl_xor(seR, 8);
        }
        s1 += __shfl_xor(s1, 16);  seR += __shfl_xor(seR, 16);
        s1 += __shfl_xor(s1, 32);  seR += __shfl_xor(seR, 32);
        // s1 = sum_i (e_i or 1) * v_i[comp], comp = lane&15 ; seR = SE

        const float s = (it == 0) ? s1 * (1.0f / 288.0f) : s1 / seR;

        // ---- squash ----
        float t2 = s * s;
        t2 += __shfl_xor(t2, 1);
        t2 += __shfl_xor(t2, 2);
        t2 += __shfl_xor(t2, 4);
        t2 += __shfl_xor(t2, 8);
        const float n2 = t2;
        const float scale = n2 / ((1.0f + n2) * sqrtf(n2 + EPS_));
        const float pval = s * scale;   // comp (lane&15) of p

        if (it < NITERS - 1) {
            float p[16];
#pragma unroll
            for (int q = 0; q < 16; ++q) p[q] = __shfl(pval, q);
            v2f p2[8];
#pragma unroll
            for (int m = 0; m < 8; ++m) p2[m] = (v2f){p[2*m], p[2*m+1]};
#pragma unroll
            for (int k = 0; k < 5; ++k) {
                v2f acc = (v2f){0.f, 0.f};
#pragma unroll
                for (int m = 0; m < 8; ++m)
                    acc = __builtin_elementwise_fma(v[k][m], p2[m], acc);
                logit[k] += acc.x + acc.y;
            }
        } else {
            if (lane < 16)
                out[(size_t)n * 512 + j * 16 + lane] = pval;
        }
    }
}

extern "C" void kernel_launch(void* const* d_in, const int* in_sizes, int n_in,
                              void* d_out, int out_size, void* d_ws, size_t ws_size,
                              hipStream_t stream) {
    const float* x = (const float*)d_in[0];
    const float* w = (const float*)d_in[1];
    float* out = (float*)d_out;
    const int nblocks = 450 * 8;   // (n) x (j-groups of 4 waves)

    const size_t need = (size_t)(XT_FLOATS + WT_FLOATS) * sizeof(float);
    if (d_ws != nullptr && ws_size >= need) {
        float* xt = (float*)d_ws;
        float* wt = xt + XT_FLOATS;
        permute_x_kernel<<<XT_FLOATS / 256, 256, 0, stream>>>(x, xt);
        permute_w_kernel<<<WT_FLOATS / 256, 256, 0, stream>>>(w, wt);
        convcaps_kernel<true><<<nblocks, 256, 0, stream>>>(xt, wt, out);
    } else {
        convcaps_kernel<false><<<nblocks, 256, 0, stream>>>(x, w, out);
    }
}

// Round 9
// 86.319 us; speedup vs baseline: 1.2310x; 1.0846x over previous
//
#include <hip/hip_runtime.h>

// ConvCapsLayer: A=32,B=32,K=3,P=4,STRIDE=2,ITERS=3 — fp32 in/out
// x: (2,32,32,512) f32   weights: (288,32,16) f32   out: (450,512) f32
//
// R9: R8 (lane-contiguous f32 staging) confirmed the TA-pipe theory.
// Now: stage x and w as BF16 (halves TA line-touches again), expand to f32
// in registers (all math stays fp32). One WAVE per block (64 thr): no
// LDS/barriers anywhere, so block granularity only hurt slot-freeing.
//   xt_bf[pixel][a][16]  (4 MB, pure cast of x)
//   wt_bf[j][k][lane][16] (320 KB, permuted + cast)
// Wave = (patch n, capsule j); lane owns i = lane + 64k, k=0..4.
// Split-first butterfly, unnormalized softmax (SE rides the butterfly).
// NOTE: __launch_bounds__ min-waves must keep VGPR cap >= live set (~84);
// forcing a 64-VGPR cap spilled 170MB to scratch (measured R4).

#define OH 15
#define OW 15
#define NITERS 3
#define EPS_ 1e-8f

#define XT_ELEMS (2 * 32 * 32 * 512)        // 2,097,152 bf16 (4 MB)
#define WT_ELEMS (32 * 5 * 64 * 16)         // 163,840 bf16 (320 KB)

typedef float v2f __attribute__((ext_vector_type(2)));

__device__ __forceinline__ v2f pfma(float a, v2f b, v2f c) {
    return __builtin_elementwise_fma((v2f){a, a}, b, c);
}
__device__ __forceinline__ float b_lo(unsigned int u) {
    union { unsigned int i; float f; } c; c.i = u << 16; return c.f;
}
__device__ __forceinline__ float b_hi(unsigned int u) {
    union { unsigned int i; float f; } c; c.i = u & 0xFFFF0000u; return c.f;
}
__device__ __forceinline__ unsigned short f2bf(float f) {
    union { float f; unsigned int i; } c; c.f = f;
    return (unsigned short)((c.i + 0x7FFFu + ((c.i >> 16) & 1u)) >> 16); // RNE
}

// cast x -> bf16, same element order
__global__ __launch_bounds__(256) void cast_x_kernel(
    const float* __restrict__ x, unsigned short* __restrict__ xt)
{
    const int tid = blockIdx.x * 256 + threadIdx.x;
    xt[tid] = f2bf(x[tid]);
}

// wt[j][k][L][e] = w[(L+64k)*512 + j*16 + e]  (bf16), zero-pad i>=288
__global__ __launch_bounds__(256) void permute_w_kernel(
    const float* __restrict__ w, unsigned short* __restrict__ wt)
{
    const int tid = blockIdx.x * 256 + threadIdx.x;   // over WT_ELEMS
    const int j  = tid / 5120;
    const int r  = tid - j * 5120;
    const int k  = r >> 10;
    const int L  = (r >> 4) & 63;
    const int e  = r & 15;
    const int i  = L + 64 * k;
    wt[tid] = (i < 288) ? f2bf(w[(size_t)i * 512 + j * 16 + e]) : (unsigned short)0;
}

template <bool PERM>
__global__ __launch_bounds__(64, 3) void convcaps_kernel(
    const void* __restrict__ xp,   // PERM ? bf16 xt : f32 x
    const void* __restrict__ wp_,  // PERM ? bf16 wt : f32 w
    float* __restrict__ out)       // (450,512)
{
    const int blk  = blockIdx.x;      // 0..14399
    const int n    = blk >> 5;        // patch 0..449
    const int j    = blk & 31;        // out capsule
    const int lane = threadIdx.x;     // 0..63

    const int batch = n / (OH * OW);
    const int rem   = n - batch * OH * OW;
    const int oy    = rem / OW;
    const int ox    = rem - oy * OW;

    const bool has5 = (lane < 32);

    v2f v[5][8];                      // v[k][p*2+qq]
    float logit[5] = {0.f, 0.f, 0.f, 0.f, 0.f};

    // ---- v[k] = X_i(4x4) * W_ij(4x4), i = lane + 64k ----
#pragma unroll
    for (int k = 0; k < 5; ++k) {
        if (k == 4 && !has5) {
#pragma unroll
            for (int m = 0; m < 8; ++m) v[4][m] = (v2f){0.f, 0.f};
        } else {
            const int i  = lane + 64 * k;
            const int a  = i & 31;
            const int kw = (i >> 5) % 3;
            const int kh = i / 96;
            const int h  = oy * 2 + kh;
            const int wc = ox * 2 + kw;
            const int pixel = (batch * 32 + h) * 32 + wc;

            float xr[16];
            v2f wr2[4][2];
            if (PERM) {
                // xt[pixel][a][16] bf16: 32B contiguous per lane
                const uint4* xb = reinterpret_cast<const uint4*>(
                    (const unsigned short*)xp + ((size_t)pixel * 512 + a * 16));
                uint4 u0 = xb[0], u1 = xb[1];
                xr[0]=b_lo(u0.x); xr[1]=b_hi(u0.x); xr[2]=b_lo(u0.y); xr[3]=b_hi(u0.y);
                xr[4]=b_lo(u0.z); xr[5]=b_hi(u0.z); xr[6]=b_lo(u0.w); xr[7]=b_hi(u0.w);
                xr[8]=b_lo(u1.x); xr[9]=b_hi(u1.x); xr[10]=b_lo(u1.y); xr[11]=b_hi(u1.y);
                xr[12]=b_lo(u1.z); xr[13]=b_hi(u1.z); xr[14]=b_lo(u1.w); xr[15]=b_hi(u1.w);
                // wt[j][k][lane][16] bf16: 32B contiguous per lane
                const uint4* wb = reinterpret_cast<const uint4*>(
                    (const unsigned short*)wp_ + (((size_t)j * 5 + k) * 64 + lane) * 16);
                uint4 q0 = wb[0], q1 = wb[1];
                // wr2[r][qq] = {w[r*4+2qq], w[r*4+2qq+1]} ; pair index r*2+qq
                wr2[0][0] = (v2f){b_lo(q0.x), b_hi(q0.x)};
                wr2[0][1] = (v2f){b_lo(q0.y), b_hi(q0.y)};
                wr2[1][0] = (v2f){b_lo(q0.z), b_hi(q0.z)};
                wr2[1][1] = (v2f){b_lo(q0.w), b_hi(q0.w)};
                wr2[2][0] = (v2f){b_lo(q1.x), b_hi(q1.x)};
                wr2[2][1] = (v2f){b_lo(q1.y), b_hi(q1.y)};
                wr2[3][0] = (v2f){b_lo(q1.z), b_hi(q1.z)};
                wr2[3][1] = (v2f){b_lo(q1.w), b_hi(q1.w)};
            } else {
                const float4* xv = reinterpret_cast<const float4*>(
                    (const float*)xp + ((size_t)pixel * 512 + a * 16));
                float4 x0 = xv[0], x1 = xv[1], x2 = xv[2], x3 = xv[3];
                float t_[16] = { x0.x,x0.y,x0.z,x0.w, x1.x,x1.y,x1.z,x1.w,
                                 x2.x,x2.y,x2.z,x2.w, x3.x,x3.y,x3.z,x3.w };
#pragma unroll
                for (int e = 0; e < 16; ++e) xr[e] = t_[e];
                const float4* wq = reinterpret_cast<const float4*>(
                    (const float*)wp_ + ((size_t)i * 32 + j) * 16);
                float4 w0 = wq[0], w1 = wq[1], w2 = wq[2], w3 = wq[3];
                wr2[0][0]=(v2f){w0.x,w0.y}; wr2[0][1]=(v2f){w0.z,w0.w};
                wr2[1][0]=(v2f){w1.x,w1.y}; wr2[1][1]=(v2f){w1.z,w1.w};
                wr2[2][0]=(v2f){w2.x,w2.y}; wr2[2][1]=(v2f){w2.z,w2.w};
                wr2[3][0]=(v2f){w3.x,w3.y}; wr2[3][1]=(v2f){w3.z,w3.w};
            }

#pragma unroll
            for (int p = 0; p < 4; ++p) {
#pragma unroll
                for (int qq = 0; qq < 2; ++qq) {
                    v2f acc = (v2f){0.f, 0.f};
                    acc = pfma(xr[p*4+0], wr2[0][qq], acc);
                    acc = pfma(xr[p*4+1], wr2[1][qq], acc);
                    acc = pfma(xr[p*4+2], wr2[2][qq], acc);
                    acc = pfma(xr[p*4+3], wr2[3][qq], acc);
                    v[k][p*2+qq] = acc;
                }
            }
        }
    }

#pragma unroll
    for (int it = 0; it < NITERS; ++it) {
        v2f c2[8];
        float se_loc;
        if (it == 0) {
#pragma unroll
            for (int m = 0; m < 8; ++m)
                c2[m] = v[0][m] + v[1][m] + v[2][m] + v[3][m] + v[4][m];
            se_loc = 0.f;  // normalizer is 288 (softmax of zeros)
        } else {
            const float e0 = __expf(logit[0]), e1 = __expf(logit[1]);
            const float e2 = __expf(logit[2]), e3 = __expf(logit[3]);
            const float e4 = __expf(logit[4]);
#pragma unroll
            for (int m = 0; m < 8; ++m)
                c2[m] = pfma(e0, v[0][m],
                        pfma(e1, v[1][m],
                        pfma(e2, v[2][m],
                        pfma(e3, v[3][m],
                        pfma(e4, v[4][m], (v2f){0.f, 0.f})))));
            se_loc = e0 + e1 + e2 + e3 + (has5 ? e4 : 0.f);
        }

        float c[16];
#pragma unroll
        for (int m = 0; m < 8; ++m) { c[2*m] = c2[m].x; c[2*m+1] = c2[m].y; }

        // ---- split-first butterfly: comp bit b -> lane bit b ----
        float seR = se_loc;
        float s8[8];
        {
            const bool b = lane & 1;
#pragma unroll
            for (int m = 0; m < 8; ++m) {
                float send = b ? c[2*m]   : c[2*m+1];
                float keep = b ? c[2*m+1] : c[2*m];
                s8[m] = keep + __shfl_xor(send, 1);
            }
            seR += __shfl_xor(seR, 1);
        }
        float s4[4];
        {
            const bool b = (lane >> 1) & 1;
#pragma unroll
            for (int m = 0; m < 4; ++m) {
                float send = b ? s8[2*m]   : s8[2*m+1];
                float keep = b ? s8[2*m+1] : s8[2*m];
                s4[m] = keep + __shfl_xor(send, 2);
            }
            seR += __shfl_xor(seR, 2);
        }
        float s2v[2];
        {
            const bool b = (lane >> 2) & 1;
#pragma unroll
            for (int m = 0; m < 2; ++m) {
                float send = b ? s4[2*m]   : s4[2*m+1];
                float keep = b ? s4[2*m+1] : s4[2*m];
                s2v[m] = keep + __shfl_xor(send, 4);
            }
            seR += __shfl_xor(seR, 4);
        }
        float s1;
        {
            const bool b = (lane >> 3) & 1;
            float send = b ? s2v[0] : s2v[1];
            float keep = b ? s2v[1] : s2v[0];
            s1 = keep + __shfl_xor(send, 8);
            seR += __shfl_xor(seR, 8);
        }
        s1 += __shfl_xor(s1, 16);  seR += __shfl_xor(seR, 16);
        s1 += __shfl_xor(s1, 32);  seR += __shfl_xor(seR, 32);

        const float s = (it == 0) ? s1 * (1.0f / 288.0f) : s1 / seR;

        // ---- squash ----
        float t2 = s * s;
        t2 += __shfl_xor(t2, 1);
        t2 += __shfl_xor(t2, 2);
        t2 += __shfl_xor(t2, 4);
        t2 += __shfl_xor(t2, 8);
        const float n2 = t2;
        const float scale = n2 / ((1.0f + n2) * sqrtf(n2 + EPS_));
        const float pval = s * scale;   // comp (lane&15) of p

        if (it < NITERS - 1) {
            float p[16];
#pragma unroll
            for (int q = 0; q < 16; ++q) p[q] = __shfl(pval, q);
            v2f p2[8];
#pragma unroll
            for (int m = 0; m < 8; ++m) p2[m] = (v2f){p[2*m], p[2*m+1]};
#pragma unroll
            for (int k = 0; k < 5; ++k) {
                v2f acc = (v2f){0.f, 0.f};
#pragma unroll
                for (int m = 0; m < 8; ++m)
                    acc = __builtin_elementwise_fma(v[k][m], p2[m], acc);
                logit[k] += acc.x + acc.y;
            }
        } else {
            if (lane < 16)
                out[(size_t)n * 512 + j * 16 + lane] = pval;
        }
    }
}

extern "C" void kernel_launch(void* const* d_in, const int* in_sizes, int n_in,
                              void* d_out, int out_size, void* d_ws, size_t ws_size,
                              hipStream_t stream) {
    const float* x = (const float*)d_in[0];
    const float* w = (const float*)d_in[1];
    float* out = (float*)d_out;
    const int nblocks = 450 * 32;   // one wave per (n, j)

    const size_t need = (size_t)(XT_ELEMS + WT_ELEMS) * sizeof(unsigned short);
    if (d_ws != nullptr && ws_size >= need) {
        unsigned short* xt = (unsigned short*)d_ws;
        unsigned short* wt = xt + XT_ELEMS;
        cast_x_kernel<<<XT_ELEMS / 256, 256, 0, stream>>>(x, xt);
        permute_w_kernel<<<WT_ELEMS / 256, 256, 0, stream>>>(w, wt);
        convcaps_kernel<true><<<nblocks, 64, 0, stream>>>(xt, wt, out);
    } else {
        convcaps_kernel<false><<<nblocks, 64, 0, stream>>>(x, w, out);
    }
}